// Round 5
// baseline (2281.599 us; speedup 1.0000x reference)
//
#include <hip/hip_runtime.h>
#include <math.h>

#define TS 10
#define TD 128
#define TE 64
#define BT 4
#define NTHR 256
#define HSTR 132          // floats per Hs row: 128+4 pad (row step = 4 banks mod 32)
#define QSTR 68           // floats per Q/K/Vd/G/t row: 64+4 pad
#define NHROWS (TS*BT)    // 40

#define HS_FLOATS (NHROWS*HSTR)    // 5280
#define BUF_FLOATS (20*QSTR)       // 1360 (per-hb 2-batch buffer)
#define P_FLOATS (2*TS*12)         // 240
#define LDS_FLOATS (HS_FLOATS + 3*BUF_FLOATS + P_FLOATS)   // 9600 -> 38400 B (4 WG/CU)

#define INVSQRT10 0.31622776601683794f

// ---------------- POS precompute (fp64, once per launch, into d_ws) ----------
__global__ void pos_kernel(float* __restrict__ pos) {
    for (int idx = threadIdx.x; idx < TS * TD; idx += blockDim.x) {
        int n = idx / TD, d = idx % TD;
        int j = d >> 1;
        double ang = (double)n / pow(1000.0, 2.0 * (double)j / (double)TD);
        double v = (d & 1) ? cos(ang) : sin(ang);
        pos[idx] = (float)v;
    }
}

// ---------------- M-row x C-col fp32 GEMM tile, register double-buffered -----
// OUT[m][c] = sum_k A[a0+m*astr+k] * W[k*ws+c].  A,O in LDS; W in global.
// K multiple of 8. Global W prefetch first (longest latency), then LDS A;
// both for step k+4 issue BEFORE the FMA block of step k.
template <int M, int C, int K, bool ADD>
__device__ __forceinline__ void gemm_f32(
    const float* __restrict__ Ap, int a0, int astr,
    const float* __restrict__ W, int ws,
    float* __restrict__ Op, int o0, int ostr,
    float scale)
{
    constexpr int CG = C / 4;
    float acc[M][C];
#pragma unroll
    for (int m = 0; m < M; m++)
#pragma unroll
        for (int c = 0; c < C; c++) acc[m][c] = 0.f;

    float4 aR0[M], aR1[M], wR0[4 * CG], wR1[4 * CG];

    auto loadW = [&](float4* wR, int k) {
#pragma unroll
        for (int kk = 0; kk < 4; kk++)
#pragma unroll
            for (int cg = 0; cg < CG; cg++)
                wR[kk * CG + cg] = *(const float4*)(W + (size_t)(k + kk) * ws + cg * 4);
    };
    auto loadA = [&](float4* aR, int k) {
#pragma unroll
        for (int m = 0; m < M; m++)
            aR[m] = *(const float4*)(Ap + a0 + m * astr + k);
    };
    auto compute = [&](const float4* aR, const float4* wR) {
#pragma unroll
        for (int m = 0; m < M; m++) {
            const float* af = (const float*)&aR[m];
#pragma unroll
            for (int kk = 0; kk < 4; kk++) {
                float a = af[kk];
#pragma unroll
                for (int cg = 0; cg < CG; cg++) {
                    const float* wf = (const float*)&wR[kk * CG + cg];
#pragma unroll
                    for (int j = 0; j < 4; j++)
                        acc[m][cg * 4 + j] = fmaf(a, wf[j], acc[m][cg * 4 + j]);
                }
            }
        }
    };

    loadW(wR0, 0); loadA(aR0, 0);
    int k = 0;
#pragma unroll 1
    for (; k + 8 < K; k += 8) {
        loadW(wR1, k + 4); loadA(aR1, k + 4);   // prefetch k+4
        compute(aR0, wR0);                      // compute k
        loadW(wR0, k + 8); loadA(aR0, k + 8);   // prefetch k+8
        compute(aR1, wR1);                      // compute k+4
    }
    loadW(wR1, K - 4); loadA(aR1, K - 4);
    compute(aR0, wR0);
    compute(aR1, wR1);

#pragma unroll
    for (int m = 0; m < M; m++) {
        float* op = Op + o0 + m * ostr;
#pragma unroll
        for (int cg = 0; cg < CG; cg++) {
            float4 r;
            if constexpr (ADD) {
                float4 v = *(float4*)(op + cg * 4);
                r.x = fmaf(scale, acc[m][cg * 4 + 0], v.x);
                r.y = fmaf(scale, acc[m][cg * 4 + 1], v.y);
                r.z = fmaf(scale, acc[m][cg * 4 + 2], v.z);
                r.w = fmaf(scale, acc[m][cg * 4 + 3], v.w);
            } else {
                r.x = scale * acc[m][cg * 4 + 0];
                r.y = scale * acc[m][cg * 4 + 1];
                r.z = scale * acc[m][cg * 4 + 2];
                r.w = scale * acc[m][cg * 4 + 3];
            }
            *(float4*)(op + cg * 4) = r;
        }
    }
}

// ---------------- fused kernel ----------------------------------------------
// BT=4, 38.4 KB LDS -> 4 WGs/CU co-resident = 4 waves/SIMD (latency hiding).
extern "C" __global__ __launch_bounds__(NTHR, 4)
void trans_fused(const float* __restrict__ x,
                 const float* __restrict__ L_w, const float* __restrict__ UL_w,
                 const float* __restrict__ WQ,  const float* __restrict__ WK,
                 const float* __restrict__ WVd, const float* __restrict__ WVu,
                 const float* __restrict__ WQ2, const float* __restrict__ WK2,
                 const float* __restrict__ WVd2,const float* __restrict__ WVu2,
                 const float* __restrict__ qin1,const float* __restrict__ qout1,
                 const float* __restrict__ qin2,const float* __restrict__ qout2,
                 const float* __restrict__ POSb, float* __restrict__ out)
{
    extern __shared__ float lds[];
    float* Hs = lds;                      // [40][HSTR], row = b*10 + n
    float* Qb = lds + HS_FLOATS;          // [20][QSTR], row r2 = b2*10 + n ; also G / t(lo)
    float* Kb = Qb + BUF_FLOATS;          // [20][QSTR]                     ; also t(hi)
    float* Vb = Kb + BUF_FLOATS;          // [20][QSTR]
    float* Pb = Vb + BUF_FLOATS;          // [2][10][12] logits -> softmax weights
    float* Tb = Qb;                       // t buffer: 40 rows spanning Qb+Kb

    const int tid = threadIdx.x;
    // Rotate partial-phase idle windows across waves per block so the four
    // co-resident WGs fill each other's gaps.
    const int vtid = (tid + ((blockIdx.x & 3) << 6)) & 255;
    const int gb0 = blockIdx.x * BT;

    // ---- Phase 0: h = x @ L_w + POS (fp64 accum; 20 elems/thread) ----
    for (int idx = tid; idx < NHROWS * TD; idx += NTHR) {
        int r = idx >> 7, d = idx & 127;
        int b = r / 10, n = r - b * 10;
        const float* xp = x + ((size_t)(gb0 + b) * TS + n) * 4;
        double acc = (double)POSb[n * TD + d];
#pragma unroll
        for (int c = 0; c < 4; c++)
            acc += (double)xp[c] * (double)L_w[c * TD + d];
        Hs[r * HSTR + d] = (float)acc;
    }
    __syncthreads();

    for (int layer = 0; layer < 2; ++layer) {
        const float* pWQ  = layer ? WQ2  : WQ;
        const float* pWK  = layer ? WK2  : WK;
        const float* pWVd = layer ? WVd2 : WVd;
        const float* pWVu = layer ? WVu2 : WVu;
        const float* pqin = layer ? qin2 : qin1;
        const float* pqou = layer ? qout2 : qout1;

        for (int hb = 0; hb < 2; ++hb) {
            // batches b = hb*2 + b2, b2 in {0,1}; Hs rows hb*20 + b2*10 + n
            // ---- QKV (fp32): 240 tasks = mat(3) x n(10) x cg(8); M over b2 ----
            if (vtid < 240) {
                int p = vtid / 80, t2 = vtid % 80;
                int n = t2 >> 3, cg = t2 & 7;
                const float* Wp = (p == 0 ? pWQ : (p == 1 ? pWK : pWVd)) + cg * 8;
                float* Ob = (p == 0 ? Qb : (p == 1 ? Kb : Vb));
                gemm_f32<2, 8, TD, false>(Hs, (hb * 20 + n) * HSTR, 10 * HSTR,
                                          Wp, TE,
                                          Ob, n * QSTR + cg * 8, 10 * QSTR, 1.f);
            }
            __syncthreads();

            // ---- logits (fp64, 2 chains): 110 = b2(2) x 55 (i,j<=i) ----
            if (vtid < 110) {
                int b2 = vtid / 55, pr = vtid % 55;
                int i = 0, base = 0;
                while (pr >= base + i + 1) { base += i + 1; i++; }
                int j = pr - base;
                const float* qr = Qb + (b2 * 10 + i) * QSTR;
                const float* kr = Kb + (b2 * 10 + j) * QSTR;
                double acc0 = 0.0, acc1 = 0.0;
                for (int e = 0; e < TE; e += 8) {
                    float4 qa = *(const float4*)(qr + e);
                    float4 ka = *(const float4*)(kr + e);
                    float4 qc = *(const float4*)(qr + e + 4);
                    float4 kc = *(const float4*)(kr + e + 4);
                    acc0 = fma((double)qa.x, (double)ka.x, acc0);
                    acc1 = fma((double)qc.x, (double)kc.x, acc1);
                    acc0 = fma((double)qa.y, (double)ka.y, acc0);
                    acc1 = fma((double)qc.y, (double)kc.y, acc1);
                    acc0 = fma((double)qa.z, (double)ka.z, acc0);
                    acc1 = fma((double)qc.z, (double)kc.z, acc1);
                    acc0 = fma((double)qa.w, (double)ka.w, acc0);
                    acc1 = fma((double)qc.w, (double)kc.w, acc1);
                }
                Pb[b2 * 120 + i * 12 + j] = (float)(acc0 + acc1);
            }
            __syncthreads();

            // ---- softmax over keys j<=i (fp32, matches reference) ----
            if (vtid < 20) {
                int b2 = vtid / 10, i = vtid % 10;
                float* pr = Pb + b2 * 120 + i * 12;
                float m = pr[0];
#pragma unroll
                for (int j = 1; j < TS; j++) if (j <= i) m = fmaxf(m, pr[j]);
                float sum = 0.f;
#pragma unroll
                for (int j = 0; j < TS; j++) if (j <= i) { float e = expf(pr[j] - m); pr[j] = e; sum += e; }
#pragma unroll
                for (int j = 0; j < TS; j++) pr[j] = (j <= i) ? pr[j] / sum : 0.f;
            }
            __syncthreads();

            // ---- G[r2=b2*10+q][e] = sum_k P * Vd[b2*10+k][e]; into Qb (Q dead) ----
            for (int oi = vtid; oi < 20 * 16; oi += NTHR) {
                int rr = oi >> 4, e4 = (oi & 15) * 4;
                int b2 = rr / 10;
                int q = rr - b2 * 10;
                const float* pp = Pb + b2 * 120 + q * 12;
                float4 g = {0.f, 0.f, 0.f, 0.f};
#pragma unroll
                for (int k = 0; k < TS; k++) {
                    float p = pp[k];
                    float4 v = *(const float4*)(Vb + (b2 * 10 + k) * QSTR + e4);
                    g.x = fmaf(p, v.x, g.x);
                    g.y = fmaf(p, v.y, g.y);
                    g.z = fmaf(p, v.z, g.z);
                    g.w = fmaf(p, v.w, g.w);
                }
                *(float4*)(Qb + rr * QSTR + e4) = g;
            }
            __syncthreads();

            // ---- DE: Hs(hb half) += invsqrt10 * G @ WVu ; 160 = q(10) x cg(16) ----
            if (vtid < 160) {
                int q = vtid >> 4, cg = vtid & 15;
                gemm_f32<2, 8, TE, true>(Qb, q * QSTR, 10 * QSTR,
                                         pWVu + cg * 8, TD,
                                         Hs, (hb * 20 + q) * HSTR + cg * 8, 10 * HSTR,
                                         INVSQRT10);
            }
            __syncthreads();
        } // hb

        // ---- ques-in: t[40][64] = Hs @ quesin[n] ; 320 = n(10) x bg(2) x cg(16) ----
        for (int task = vtid; task < 320; task += NTHR) {
            int cg = task & 15, bg = (task >> 4) & 1, n = task >> 5;
            gemm_f32<2, 4, TD, false>(Hs, (bg * 20 + n) * HSTR, 10 * HSTR,
                                      pqin + (size_t)n * TD * TE + cg * 4, TE,
                                      Tb, (bg * 20 + n) * QSTR + cg * 4, 10 * QSTR, 1.f);
        }
        __syncthreads();

        // ---- ques-out: Hs = t @ quesout[n] ; 320 = n(10) x bg(2) x cg(16) ----
        for (int task = vtid; task < 320; task += NTHR) {
            int cg = task & 15, bg = (task >> 4) & 1, n = task >> 5;
            gemm_f32<2, 8, TE, false>(Tb, (bg * 20 + n) * QSTR, 10 * QSTR,
                                      pqou + (size_t)n * TE * TD + cg * 8, TD,
                                      Hs, (bg * 20 + n) * HSTR + cg * 8, 10 * HSTR, 1.f);
        }
        __syncthreads();
    } // layer

    // ---- out = Hs @ UL_w : 160 outs ----
    if (vtid < NHROWS * 4) {
        int r = vtid >> 2, c = vtid & 3;
        int b = r / 10, n = r - b * 10;
        const float* hr = Hs + r * HSTR;
        float acc = 0.f;
        for (int d = 0; d < TD; d += 4) {
            float4 h4 = *(const float4*)(hr + d);
            acc = fmaf(h4.x, UL_w[(d + 0) * 4 + c], acc);
            acc = fmaf(h4.y, UL_w[(d + 1) * 4 + c], acc);
            acc = fmaf(h4.z, UL_w[(d + 2) * 4 + c], acc);
            acc = fmaf(h4.w, UL_w[(d + 3) * 4 + c], acc);
        }
        out[((size_t)(gb0 + b) * TS + n) * 4 + c] = acc;
    }
}

// ---------------- host launch -----------------------------------------------
extern "C" void kernel_launch(void* const* d_in, const int* in_sizes, int n_in,
                              void* d_out, int out_size, void* d_ws, size_t ws_size,
                              hipStream_t stream) {
    const float* x    = (const float*)d_in[0];
    const float* L_w  = (const float*)d_in[1];
    const float* UL_w = (const float*)d_in[2];
    const float* WQ   = (const float*)d_in[3];
    const float* WK   = (const float*)d_in[4];
    const float* WVd  = (const float*)d_in[5];
    const float* WVu  = (const float*)d_in[6];
    const float* WQ2  = (const float*)d_in[7];
    const float* WK2  = (const float*)d_in[8];
    const float* WVd2 = (const float*)d_in[9];
    const float* WVu2 = (const float*)d_in[10];
    const float* qin1 = (const float*)d_in[11];
    const float* qout1= (const float*)d_in[12];
    const float* qin2 = (const float*)d_in[13];
    const float* qout2= (const float*)d_in[14];
    float* out = (float*)d_out;
    float* POSb = (float*)d_ws;

    int B = in_sizes[0] / (TS * 4);
    size_t lds_bytes = (size_t)LDS_FLOATS * sizeof(float);

    (void)hipFuncSetAttribute((const void*)trans_fused,
                              hipFuncAttributeMaxDynamicSharedMemorySize,
                              (int)lds_bytes);

    pos_kernel<<<dim3(1), dim3(256), 0, stream>>>(POSb);
    trans_fused<<<dim3(B / BT), dim3(NTHR), lds_bytes, stream>>>(
        x, L_w, UL_w, WQ, WK, WVd, WVu, WQ2, WK2, WVd2, WVu2,
        qin1, qout1, qin2, qout2, POSb, out);
}

// Round 6
// 2165.188 us; speedup vs baseline: 1.0538x; 1.0538x over previous
//
#include <hip/hip_runtime.h>
#include <math.h>

#define TS 10
#define TD 128
#define TE 64
#define BT 4
#define NTHR 256
#define HSTR 132          // floats per Hs row: 128+4 pad (row step = 4 banks mod 32)
#define QSTR 68           // floats per Q/K/Vd/G/t row: 64+4 pad
#define NHROWS (TS*BT)    // 40

#define HS_FLOATS (NHROWS*HSTR)    // 5280
#define BUF_FLOATS (20*QSTR)       // 1360 (per-hb 2-batch buffer)
#define P_FLOATS (2*TS*12)         // 240
#define LDS_FLOATS (HS_FLOATS + 3*BUF_FLOATS + P_FLOATS)   // 9600 -> 38400 B (4 WG/CU by LDS)

#define INVSQRT10 0.31622776601683794f

// ---------------- POS precompute (fp64, once per launch, into d_ws) ----------
__global__ void pos_kernel(float* __restrict__ pos) {
    for (int idx = threadIdx.x; idx < TS * TD; idx += blockDim.x) {
        int n = idx / TD, d = idx % TD;
        int j = d >> 1;
        double ang = (double)n / pow(1000.0, 2.0 * (double)j / (double)TD);
        double v = (d & 1) ? cos(ang) : sin(ang);
        pos[idx] = (float)v;
    }
}

// ---------------- M-row x C-col fp32 GEMM tile, register double-buffered -----
// OUT[m][c] = sum_k A[a0+m*astr+k] * W[k*ws+c].  A,O in LDS; W in global.
// K multiple of 8. Global W prefetch first (longest latency), then LDS A;
// both for step k+4 issue BEFORE the FMA block of step k.
template <int M, int C, int K, bool ADD>
__device__ __forceinline__ void gemm_f32(
    const float* __restrict__ Ap, int a0, int astr,
    const float* __restrict__ W, int ws,
    float* __restrict__ Op, int o0, int ostr,
    float scale)
{
    constexpr int CG = C / 4;
    float acc[M][C];
#pragma unroll
    for (int m = 0; m < M; m++)
#pragma unroll
        for (int c = 0; c < C; c++) acc[m][c] = 0.f;

    float4 aR0[M], aR1[M], wR0[4 * CG], wR1[4 * CG];

    auto loadW = [&](float4* wR, int k) {
#pragma unroll
        for (int kk = 0; kk < 4; kk++)
#pragma unroll
            for (int cg = 0; cg < CG; cg++)
                wR[kk * CG + cg] = *(const float4*)(W + (size_t)(k + kk) * ws + cg * 4);
    };
    auto loadA = [&](float4* aR, int k) {
#pragma unroll
        for (int m = 0; m < M; m++)
            aR[m] = *(const float4*)(Ap + a0 + m * astr + k);
    };
    auto compute = [&](const float4* aR, const float4* wR) {
#pragma unroll
        for (int m = 0; m < M; m++) {
            const float* af = (const float*)&aR[m];
#pragma unroll
            for (int kk = 0; kk < 4; kk++) {
                float a = af[kk];
#pragma unroll
                for (int cg = 0; cg < CG; cg++) {
                    const float* wf = (const float*)&wR[kk * CG + cg];
#pragma unroll
                    for (int j = 0; j < 4; j++)
                        acc[m][cg * 4 + j] = fmaf(a, wf[j], acc[m][cg * 4 + j]);
                }
            }
        }
    };

    loadW(wR0, 0); loadA(aR0, 0);
    int k = 0;
#pragma unroll 1
    for (; k + 8 < K; k += 8) {
        loadW(wR1, k + 4); loadA(aR1, k + 4);   // prefetch k+4
        compute(aR0, wR0);                      // compute k
        loadW(wR0, k + 8); loadA(aR0, k + 8);   // prefetch k+8
        compute(aR1, wR1);                      // compute k+4
    }
    loadW(wR1, K - 4); loadA(aR1, K - 4);
    compute(aR0, wR0);
    compute(aR1, wR1);

#pragma unroll
    for (int m = 0; m < M; m++) {
        float* op = Op + o0 + m * ostr;
#pragma unroll
        for (int cg = 0; cg < CG; cg++) {
            float4 r;
            if constexpr (ADD) {
                float4 v = *(float4*)(op + cg * 4);
                r.x = fmaf(scale, acc[m][cg * 4 + 0], v.x);
                r.y = fmaf(scale, acc[m][cg * 4 + 1], v.y);
                r.z = fmaf(scale, acc[m][cg * 4 + 2], v.z);
                r.w = fmaf(scale, acc[m][cg * 4 + 3], v.w);
            } else {
                r.x = scale * acc[m][cg * 4 + 0];
                r.y = scale * acc[m][cg * 4 + 1];
                r.z = scale * acc[m][cg * 4 + 2];
                r.w = scale * acc[m][cg * 4 + 3];
            }
            *(float4*)(op + cg * 4) = r;
        }
    }
}

// ---------------- fused kernel ----------------------------------------------
// BT=4, 38.4 KB LDS -> LDS admits 4 WGs/CU; bounds (256,2) keeps VGPR=128
// (spill-free, R3/R4-verified), and 128 VGPR also admits 4 waves/SIMD.
extern "C" __global__ __launch_bounds__(NTHR, 2)
void trans_fused(const float* __restrict__ x,
                 const float* __restrict__ L_w, const float* __restrict__ UL_w,
                 const float* __restrict__ WQ,  const float* __restrict__ WK,
                 const float* __restrict__ WVd, const float* __restrict__ WVu,
                 const float* __restrict__ WQ2, const float* __restrict__ WK2,
                 const float* __restrict__ WVd2,const float* __restrict__ WVu2,
                 const float* __restrict__ qin1,const float* __restrict__ qout1,
                 const float* __restrict__ qin2,const float* __restrict__ qout2,
                 const float* __restrict__ POSb, float* __restrict__ out)
{
    extern __shared__ float lds[];
    float* Hs = lds;                      // [40][HSTR], row = b*10 + n
    float* Qb = lds + HS_FLOATS;          // [20][QSTR], row r2 = b2*10 + n ; also G / t(lo)
    float* Kb = Qb + BUF_FLOATS;          // [20][QSTR]                     ; also t(hi)
    float* Vb = Kb + BUF_FLOATS;          // [20][QSTR]
    float* Pb = Vb + BUF_FLOATS;          // [2][10][12] logits -> softmax weights
    float* Tb = Qb;                       // t buffer: 40 rows spanning Qb+Kb

    const int tid = threadIdx.x;
    // Rotate partial-phase idle windows across waves per block so co-resident
    // WGs fill each other's gaps.
    const int vtid = (tid + ((blockIdx.x & 3) << 6)) & 255;
    const int gb0 = blockIdx.x * BT;

    // ---- Phase 0: h = x @ L_w + POS (fp64 accum; 20 elems/thread) ----
    for (int idx = tid; idx < NHROWS * TD; idx += NTHR) {
        int r = idx >> 7, d = idx & 127;
        int b = r / 10, n = r - b * 10;
        const float* xp = x + ((size_t)(gb0 + b) * TS + n) * 4;
        double acc = (double)POSb[n * TD + d];
#pragma unroll
        for (int c = 0; c < 4; c++)
            acc += (double)xp[c] * (double)L_w[c * TD + d];
        Hs[r * HSTR + d] = (float)acc;
    }
    __syncthreads();

    for (int layer = 0; layer < 2; ++layer) {
        const float* pWQ  = layer ? WQ2  : WQ;
        const float* pWK  = layer ? WK2  : WK;
        const float* pWVd = layer ? WVd2 : WVd;
        const float* pWVu = layer ? WVu2 : WVu;
        const float* pqin = layer ? qin2 : qin1;
        const float* pqou = layer ? qout2 : qout1;

        for (int hb = 0; hb < 2; ++hb) {
            // batches b = hb*2 + b2, b2 in {0,1}; Hs rows hb*20 + b2*10 + n
            // ---- QKV (fp32): 240 tasks = mat(3) x n(10) x cg(8); M over b2 ----
            if (vtid < 240) {
                int p = vtid / 80, t2 = vtid % 80;
                int n = t2 >> 3, cg = t2 & 7;
                const float* Wp = (p == 0 ? pWQ : (p == 1 ? pWK : pWVd)) + cg * 8;
                float* Ob = (p == 0 ? Qb : (p == 1 ? Kb : Vb));
                gemm_f32<2, 8, TD, false>(Hs, (hb * 20 + n) * HSTR, 10 * HSTR,
                                          Wp, TE,
                                          Ob, n * QSTR + cg * 8, 10 * QSTR, 1.f);
            }
            __syncthreads();

            // ---- logits (fp64, 2 chains): 110 = b2(2) x 55 (i,j<=i) ----
            if (vtid < 110) {
                int b2 = vtid / 55, pr = vtid % 55;
                int i = 0, base = 0;
                while (pr >= base + i + 1) { base += i + 1; i++; }
                int j = pr - base;
                const float* qr = Qb + (b2 * 10 + i) * QSTR;
                const float* kr = Kb + (b2 * 10 + j) * QSTR;
                double acc0 = 0.0, acc1 = 0.0;
                for (int e = 0; e < TE; e += 8) {
                    float4 qa = *(const float4*)(qr + e);
                    float4 ka = *(const float4*)(kr + e);
                    float4 qc = *(const float4*)(qr + e + 4);
                    float4 kc = *(const float4*)(kr + e + 4);
                    acc0 = fma((double)qa.x, (double)ka.x, acc0);
                    acc1 = fma((double)qc.x, (double)kc.x, acc1);
                    acc0 = fma((double)qa.y, (double)ka.y, acc0);
                    acc1 = fma((double)qc.y, (double)kc.y, acc1);
                    acc0 = fma((double)qa.z, (double)ka.z, acc0);
                    acc1 = fma((double)qc.z, (double)kc.z, acc1);
                    acc0 = fma((double)qa.w, (double)ka.w, acc0);
                    acc1 = fma((double)qc.w, (double)kc.w, acc1);
                }
                Pb[b2 * 120 + i * 12 + j] = (float)(acc0 + acc1);
            }
            __syncthreads();

            // ---- softmax over keys j<=i (fp32, matches reference) ----
            if (vtid < 20) {
                int b2 = vtid / 10, i = vtid % 10;
                float* pr = Pb + b2 * 120 + i * 12;
                float m = pr[0];
#pragma unroll
                for (int j = 1; j < TS; j++) if (j <= i) m = fmaxf(m, pr[j]);
                float sum = 0.f;
#pragma unroll
                for (int j = 0; j < TS; j++) if (j <= i) { float e = expf(pr[j] - m); pr[j] = e; sum += e; }
#pragma unroll
                for (int j = 0; j < TS; j++) pr[j] = (j <= i) ? pr[j] / sum : 0.f;
            }
            __syncthreads();

            // ---- G[r2=b2*10+q][e] = sum_k P * Vd[b2*10+k][e]; into Qb (Q dead) ----
            for (int oi = vtid; oi < 20 * 16; oi += NTHR) {
                int rr = oi >> 4, e4 = (oi & 15) * 4;
                int b2 = rr / 10;
                int q = rr - b2 * 10;
                const float* pp = Pb + b2 * 120 + q * 12;
                float4 g = {0.f, 0.f, 0.f, 0.f};
#pragma unroll
                for (int k = 0; k < TS; k++) {
                    float p = pp[k];
                    float4 v = *(const float4*)(Vb + (b2 * 10 + k) * QSTR + e4);
                    g.x = fmaf(p, v.x, g.x);
                    g.y = fmaf(p, v.y, g.y);
                    g.z = fmaf(p, v.z, g.z);
                    g.w = fmaf(p, v.w, g.w);
                }
                *(float4*)(Qb + rr * QSTR + e4) = g;
            }
            __syncthreads();

            // ---- DE: Hs(hb half) += invsqrt10 * G @ WVu ; 160 = q(10) x cg(16) ----
            if (vtid < 160) {
                int q = vtid >> 4, cg = vtid & 15;
                gemm_f32<2, 8, TE, true>(Qb, q * QSTR, 10 * QSTR,
                                         pWVu + cg * 8, TD,
                                         Hs, (hb * 20 + q) * HSTR + cg * 8, 10 * HSTR,
                                         INVSQRT10);
            }
            __syncthreads();
        } // hb

        // ---- ques-in: t[40][64] = Hs @ quesin[n] ; 320 = n(10) x bg(2) x cg(16) ----
        for (int task = vtid; task < 320; task += NTHR) {
            int cg = task & 15, bg = (task >> 4) & 1, n = task >> 5;
            gemm_f32<2, 4, TD, false>(Hs, (bg * 20 + n) * HSTR, 10 * HSTR,
                                      pqin + (size_t)n * TD * TE + cg * 4, TE,
                                      Tb, (bg * 20 + n) * QSTR + cg * 4, 10 * QSTR, 1.f);
        }
        __syncthreads();

        // ---- ques-out: Hs = t @ quesout[n] ; 320 = n(10) x bg(2) x cg(16) ----
        for (int task = vtid; task < 320; task += NTHR) {
            int cg = task & 15, bg = (task >> 4) & 1, n = task >> 5;
            gemm_f32<2, 8, TE, false>(Tb, (bg * 20 + n) * QSTR, 10 * QSTR,
                                      pqou + (size_t)n * TE * TD + cg * 8, TD,
                                      Hs, (bg * 20 + n) * HSTR + cg * 8, 10 * HSTR, 1.f);
        }
        __syncthreads();
    } // layer

    // ---- out = Hs @ UL_w : 160 outs ----
    if (vtid < NHROWS * 4) {
        int r = vtid >> 2, c = vtid & 3;
        int b = r / 10, n = r - b * 10;
        const float* hr = Hs + r * HSTR;
        float acc = 0.f;
        for (int d = 0; d < TD; d += 4) {
            float4 h4 = *(const float4*)(hr + d);
            acc = fmaf(h4.x, UL_w[(d + 0) * 4 + c], acc);
            acc = fmaf(h4.y, UL_w[(d + 1) * 4 + c], acc);
            acc = fmaf(h4.z, UL_w[(d + 2) * 4 + c], acc);
            acc = fmaf(h4.w, UL_w[(d + 3) * 4 + c], acc);
        }
        out[((size_t)(gb0 + b) * TS + n) * 4 + c] = acc;
    }
}

// ---------------- host launch -----------------------------------------------
extern "C" void kernel_launch(void* const* d_in, const int* in_sizes, int n_in,
                              void* d_out, int out_size, void* d_ws, size_t ws_size,
                              hipStream_t stream) {
    const float* x    = (const float*)d_in[0];
    const float* L_w  = (const float*)d_in[1];
    const float* UL_w = (const float*)d_in[2];
    const float* WQ   = (const float*)d_in[3];
    const float* WK   = (const float*)d_in[4];
    const float* WVd  = (const float*)d_in[5];
    const float* WVu  = (const float*)d_in[6];
    const float* WQ2  = (const float*)d_in[7];
    const float* WK2  = (const float*)d_in[8];
    const float* WVd2 = (const float*)d_in[9];
    const float* WVu2 = (const float*)d_in[10];
    const float* qin1 = (const float*)d_in[11];
    const float* qout1= (const float*)d_in[12];
    const float* qin2 = (const float*)d_in[13];
    const float* qout2= (const float*)d_in[14];
    float* out = (float*)d_out;
    float* POSb = (float*)d_ws;

    int B = in_sizes[0] / (TS * 4);
    size_t lds_bytes = (size_t)LDS_FLOATS * sizeof(float);

    (void)hipFuncSetAttribute((const void*)trans_fused,
                              hipFuncAttributeMaxDynamicSharedMemorySize,
                              (int)lds_bytes);

    pos_kernel<<<dim3(1), dim3(256), 0, stream>>>(POSb);
    trans_fused<<<dim3(B / BT), dim3(NTHR), lds_bytes, stream>>>(
        x, L_w, UL_w, WQ, WK, WVd, WVu, WQ2, WK2, WVd2, WVu2,
        qin1, qout1, qin2, qout2, POSb, out);
}

// Round 7
// 1412.135 us; speedup vs baseline: 1.6157x; 1.5333x over previous
//
#include <hip/hip_runtime.h>
#include <math.h>

#define TS 10
#define TD 128
#define TE 64
#define BT 4
#define NTHR 256
#define HSTR 132          // floats per Hs row: 128+4 pad (row f4-step = 33 -> bank spread)
#define QSTR 68           // floats per Q/K/Vd/G/t row: 64+4 pad (f4-step 17)
#define NHROWS (TS*BT)    // 40

#define HS_FLOATS (NHROWS*HSTR)    // 5280
#define BUF_FLOATS (NHROWS*QSTR)   // 2720 (full 4-batch buffer)
#define P_FLOATS (BT*TS*12)        // 480
#define LDS_FLOATS (HS_FLOATS + 2*BUF_FLOATS + P_FLOATS)   // 11200 -> 44800 B

#define INVSQRT10 0.31622776601683794f

// ---------------- POS precompute (fp64, once per launch, into d_ws) ----------
__global__ void pos_kernel(float* __restrict__ pos) {
    for (int idx = threadIdx.x; idx < TS * TD; idx += blockDim.x) {
        int n = idx / TD, d = idx % TD;
        int j = d >> 1;
        double ang = (double)n / pow(1000.0, 2.0 * (double)j / (double)TD);
        double v = (d & 1) ? cos(ang) : sin(ang);
        pos[idx] = (float)v;
    }
}

// ---------------- M-row x C-col fp32 GEMM tile, register double-buffered -----
// OUT[m][c] = sum_k A[row(m)+k] * W[k*ws+c],  row(m) = a0 + (m/SPLIT)*aHi + (m%SPLIT)*aLo.
// A,O in LDS; W in global. K multiple of 8. W+A for step k+4 prefetched before
// the FMA block of step k. M=8 doubles FMA-per-prefetch vs M=4: per k4-step
// 8*4*C FMAs (512 issue-cycles at C=4) cover W L1/L2 latency even at 2 waves/SIMD,
// and W traffic is 4/M = 0.5 B/FMA.
template <int M, int SPLIT, int C, int K, bool ADD>
__device__ __forceinline__ void gemm_f32(
    const float* __restrict__ Ap, int a0, int aHi, int aLo,
    const float* __restrict__ W, int ws,
    float* __restrict__ Op, int o0, int oHi, int oLo,
    float scale)
{
    constexpr int CG = C / 4;
    float acc[M][C];
#pragma unroll
    for (int m = 0; m < M; m++)
#pragma unroll
        for (int c = 0; c < C; c++) acc[m][c] = 0.f;

    float4 aR0[M], aR1[M], wR0[4 * CG], wR1[4 * CG];

    auto loadW = [&](float4* wR, int k) {
#pragma unroll
        for (int kk = 0; kk < 4; kk++)
#pragma unroll
            for (int cg = 0; cg < CG; cg++)
                wR[kk * CG + cg] = *(const float4*)(W + (size_t)(k + kk) * ws + cg * 4);
    };
    auto loadA = [&](float4* aR, int k) {
#pragma unroll
        for (int m = 0; m < M; m++)
            aR[m] = *(const float4*)(Ap + a0 + (m / SPLIT) * aHi + (m % SPLIT) * aLo + k);
    };
    auto compute = [&](const float4* aR, const float4* wR) {
#pragma unroll
        for (int m = 0; m < M; m++) {
            const float* af = (const float*)&aR[m];
#pragma unroll
            for (int kk = 0; kk < 4; kk++) {
                float a = af[kk];
#pragma unroll
                for (int cg = 0; cg < CG; cg++) {
                    const float* wf = (const float*)&wR[kk * CG + cg];
#pragma unroll
                    for (int j = 0; j < 4; j++)
                        acc[m][cg * 4 + j] = fmaf(a, wf[j], acc[m][cg * 4 + j]);
                }
            }
        }
    };

    loadW(wR0, 0); loadA(aR0, 0);
#pragma unroll 1
    for (int k = 0; k + 8 < K; k += 8) {
        loadW(wR1, k + 4); loadA(aR1, k + 4);   // prefetch k+4
        compute(aR0, wR0);                      // compute k
        loadW(wR0, k + 8); loadA(aR0, k + 8);   // prefetch k+8
        compute(aR1, wR1);                      // compute k+4
    }
    loadW(wR1, K - 4); loadA(aR1, K - 4);
    compute(aR0, wR0);
    compute(aR1, wR1);

#pragma unroll
    for (int m = 0; m < M; m++) {
        float* op = Op + o0 + (m / SPLIT) * oHi + (m % SPLIT) * oLo;
#pragma unroll
        for (int cg = 0; cg < CG; cg++) {
            float4 r;
            if constexpr (ADD) {
                float4 v = *(float4*)(op + cg * 4);
                r.x = fmaf(scale, acc[m][cg * 4 + 0], v.x);
                r.y = fmaf(scale, acc[m][cg * 4 + 1], v.y);
                r.z = fmaf(scale, acc[m][cg * 4 + 2], v.z);
                r.w = fmaf(scale, acc[m][cg * 4 + 3], v.w);
            } else {
                r.x = scale * acc[m][cg * 4 + 0];
                r.y = scale * acc[m][cg * 4 + 1];
                r.z = scale * acc[m][cg * 4 + 2];
                r.w = scale * acc[m][cg * 4 + 3];
            }
            *(float4*)(op + cg * 4) = r;
        }
    }
}

// ---------------- fused kernel ----------------------------------------------
// BT=4, no hb split. Two shared activation buffers: Ab = Q -> Vd -> t,
// Bb = K -> G. 44.8 KB LDS. M=8 task tiling = 4 batches x (n, n+5).
extern "C" __global__ __launch_bounds__(NTHR, 2)
void trans_fused(const float* __restrict__ x,
                 const float* __restrict__ L_w, const float* __restrict__ UL_w,
                 const float* __restrict__ WQ,  const float* __restrict__ WK,
                 const float* __restrict__ WVd, const float* __restrict__ WVu,
                 const float* __restrict__ WQ2, const float* __restrict__ WK2,
                 const float* __restrict__ WVd2,const float* __restrict__ WVu2,
                 const float* __restrict__ qin1,const float* __restrict__ qout1,
                 const float* __restrict__ qin2,const float* __restrict__ qout2,
                 const float* __restrict__ POSb, float* __restrict__ out)
{
    extern __shared__ float lds[];
    float* Hs = lds;                      // [40][HSTR], row = b*10 + n
    float* Ab = lds + HS_FLOATS;          // [40][QSTR]: Q, then Vd, then t
    float* Bb = Ab + BUF_FLOATS;          // [40][QSTR]: K, then G
    float* Pb = Bb + BUF_FLOATS;          // [4][10][12] logits -> softmax weights

    const int tid = threadIdx.x;
    const int vtid = (tid + ((blockIdx.x & 3) << 6)) & 255;  // rotate idle windows
    const int gb0 = blockIdx.x * BT;

    // ---- Phase 0: h = x @ L_w + POS (fp64 accum) ----
    for (int idx = tid; idx < NHROWS * TD; idx += NTHR) {
        int r = idx >> 7, d = idx & 127;
        int b = r / 10, n = r - b * 10;
        const float* xp = x + ((size_t)(gb0 + b) * TS + n) * 4;
        double acc = (double)POSb[n * TD + d];
#pragma unroll
        for (int c = 0; c < 4; c++)
            acc += (double)xp[c] * (double)L_w[c * TD + d];
        Hs[r * HSTR + d] = (float)acc;
    }
    __syncthreads();

    for (int layer = 0; layer < 2; ++layer) {
        const float* pWQ  = layer ? WQ2  : WQ;
        const float* pWK  = layer ? WK2  : WK;
        const float* pWVd = layer ? WVd2 : WVd;
        const float* pWVu = layer ? WVu2 : WVu;
        const float* pqin = layer ? qin2 : qin1;
        const float* pqou = layer ? qout2 : qout1;

        // ---- QK: 160 tasks = mat(2) x np(5) x cg(16); M=8 = 4b x (n,n+5) ----
        if (vtid < 160) {
            int p = vtid / 80, t2 = vtid % 80;
            int np = t2 >> 4, cg = t2 & 15;
            const float* Wp = (p ? pWK : pWQ) + cg * 4;
            float* Ob = p ? Bb : Ab;
            gemm_f32<8, 2, 4, TD, false>(
                Hs, np * HSTR, 10 * HSTR, 5 * HSTR,
                Wp, TE,
                Ob, np * QSTR + cg * 4, 10 * QSTR, 5 * QSTR, 1.f);
        }
        __syncthreads();

        // ---- logits (fp64, 2 chains): 220 = b(4) x 55 (i,j<=i) ----
        if (vtid < 220) {
            int b = vtid / 55, pr = vtid % 55;
            int i = 0, base = 0;
            while (pr >= base + i + 1) { base += i + 1; i++; }
            int j = pr - base;
            const float* qr = Ab + (b * 10 + i) * QSTR;
            const float* kr = Bb + (b * 10 + j) * QSTR;
            double acc0 = 0.0, acc1 = 0.0;
            for (int e = 0; e < TE; e += 8) {
                float4 qa = *(const float4*)(qr + e);
                float4 ka = *(const float4*)(kr + e);
                float4 qc = *(const float4*)(qr + e + 4);
                float4 kc = *(const float4*)(kr + e + 4);
                acc0 = fma((double)qa.x, (double)ka.x, acc0);
                acc1 = fma((double)qc.x, (double)kc.x, acc1);
                acc0 = fma((double)qa.y, (double)ka.y, acc0);
                acc1 = fma((double)qc.y, (double)kc.y, acc1);
                acc0 = fma((double)qa.z, (double)ka.z, acc0);
                acc1 = fma((double)qc.z, (double)kc.z, acc1);
                acc0 = fma((double)qa.w, (double)ka.w, acc0);
                acc1 = fma((double)qc.w, (double)kc.w, acc1);
            }
            Pb[b * 120 + i * 12 + j] = (float)(acc0 + acc1);
        }
        __syncthreads();

        // ---- Vd (80 tasks, overwrites Ab; Q dead) || softmax (40 tasks) ----
        if (vtid < 80) {
            int np = vtid >> 4, cg = vtid & 15;
            gemm_f32<8, 2, 4, TD, false>(
                Hs, np * HSTR, 10 * HSTR, 5 * HSTR,
                pWVd + cg * 4, TE,
                Ab, np * QSTR + cg * 4, 10 * QSTR, 5 * QSTR, 1.f);
        } else if (vtid < 120) {
            int s = vtid - 80;
            int b = s / 10, i = s % 10;
            float* pr = Pb + b * 120 + i * 12;
            float m = pr[0];
#pragma unroll
            for (int j = 1; j < TS; j++) if (j <= i) m = fmaxf(m, pr[j]);
            float sum = 0.f;
#pragma unroll
            for (int j = 0; j < TS; j++) if (j <= i) { float e = expf(pr[j] - m); pr[j] = e; sum += e; }
#pragma unroll
            for (int j = 0; j < TS; j++) pr[j] = (j <= i) ? pr[j] / sum : 0.f;
        }
        __syncthreads();

        // ---- G[r=b*10+q][e] = sum_k P * Vd[b*10+k][e] -> Bb (K dead) ----
        for (int oi = vtid; oi < 40 * 16; oi += NTHR) {
            int rr = oi >> 4, e4 = (oi & 15) * 4;
            int b = rr / 10, q = rr - b * 10;
            const float* pp = Pb + b * 120 + q * 12;
            float4 g = {0.f, 0.f, 0.f, 0.f};
#pragma unroll
            for (int k = 0; k < TS; k++) {
                float p = pp[k];
                float4 v = *(const float4*)(Ab + (b * 10 + k) * QSTR + e4);
                g.x = fmaf(p, v.x, g.x);
                g.y = fmaf(p, v.y, g.y);
                g.z = fmaf(p, v.z, g.z);
                g.w = fmaf(p, v.w, g.w);
            }
            *(float4*)(Bb + rr * QSTR + e4) = g;
        }
        __syncthreads();

        // ---- DE: Hs += invsqrt10 * G @ WVu ; 160 = qp(5) x cg(32), M=8 ----
        if (vtid < 160) {
            int qp = vtid >> 5, cg = vtid & 31;
            gemm_f32<8, 2, 4, TE, true>(
                Bb, qp * QSTR, 10 * QSTR, 5 * QSTR,
                pWVu + cg * 4, TD,
                Hs, qp * HSTR + cg * 4, 10 * HSTR, 5 * HSTR, INVSQRT10);
        }
        __syncthreads();

        // ---- ques-in: t = Hs @ quesin[n] -> Ab (Vd dead); 160 = n(10) x cg(16), M=4 ----
        if (vtid < 160) {
            int n = vtid >> 4, cg = vtid & 15;
            gemm_f32<4, 1, 4, TD, false>(
                Hs, n * HSTR, 10 * HSTR, 0,
                pqin + (size_t)n * TD * TE + cg * 4, TE,
                Ab, n * QSTR + cg * 4, 10 * QSTR, 0, 1.f);
        }
        __syncthreads();

        // ---- ques-out: Hs = t @ quesout[n] ; 160 = n(10) x cg(16), M=4 C=8 ----
        if (vtid < 160) {
            int n = vtid >> 4, cg = vtid & 15;
            gemm_f32<4, 1, 8, TE, false>(
                Ab, n * QSTR, 10 * QSTR, 0,
                pqou + (size_t)n * TE * TD + cg * 8, TD,
                Hs, n * HSTR + cg * 8, 10 * HSTR, 0, 1.f);
        }
        __syncthreads();
    } // layer

    // ---- out = Hs @ UL_w : 160 outs ----
    if (vtid < NHROWS * 4) {
        int r = vtid >> 2, c = vtid & 3;
        int b = r / 10, n = r - b * 10;
        const float* hr = Hs + r * HSTR;
        float acc = 0.f;
        for (int d = 0; d < TD; d += 4) {
            float4 h4 = *(const float4*)(hr + d);
            acc = fmaf(h4.x, UL_w[(d + 0) * 4 + c], acc);
            acc = fmaf(h4.y, UL_w[(d + 1) * 4 + c], acc);
            acc = fmaf(h4.z, UL_w[(d + 2) * 4 + c], acc);
            acc = fmaf(h4.w, UL_w[(d + 3) * 4 + c], acc);
        }
        out[((size_t)(gb0 + b) * TS + n) * 4 + c] = acc;
    }
}

// ---------------- host launch -----------------------------------------------
extern "C" void kernel_launch(void* const* d_in, const int* in_sizes, int n_in,
                              void* d_out, int out_size, void* d_ws, size_t ws_size,
                              hipStream_t stream) {
    const float* x    = (const float*)d_in[0];
    const float* L_w  = (const float*)d_in[1];
    const float* UL_w = (const float*)d_in[2];
    const float* WQ   = (const float*)d_in[3];
    const float* WK   = (const float*)d_in[4];
    const float* WVd  = (const float*)d_in[5];
    const float* WVu  = (const float*)d_in[6];
    const float* WQ2  = (const float*)d_in[7];
    const float* WK2  = (const float*)d_in[8];
    const float* WVd2 = (const float*)d_in[9];
    const float* WVu2 = (const float*)d_in[10];
    const float* qin1 = (const float*)d_in[11];
    const float* qout1= (const float*)d_in[12];
    const float* qin2 = (const float*)d_in[13];
    const float* qout2= (const float*)d_in[14];
    float* out = (float*)d_out;
    float* POSb = (float*)d_ws;

    int B = in_sizes[0] / (TS * 4);
    size_t lds_bytes = (size_t)LDS_FLOATS * sizeof(float);

    (void)hipFuncSetAttribute((const void*)trans_fused,
                              hipFuncAttributeMaxDynamicSharedMemorySize,
                              (int)lds_bytes);

    pos_kernel<<<dim3(1), dim3(256), 0, stream>>>(POSb);
    trans_fused<<<dim3(B / BT), dim3(NTHR), lds_bytes, stream>>>(
        x, L_w, UL_w, WQ, WK, WVd, WVu, WQ2, WK2, WVd2, WVu2,
        qin1, qout1, qin2, qout2, POSb, out);
}

// Round 8
// 1190.240 us; speedup vs baseline: 1.9169x; 1.1864x over previous
//
#include <hip/hip_runtime.h>
#include <math.h>

#define TS 10
#define TD 128
#define TE 64
#define BT 8
#define NTHR 256
#define HSTR 132          // floats per Hs row: 128+4 pad
#define QSTR 68           // floats per Q/K/Vd/G/t row: 64+4 pad
#define NHROWS (TS*BT)    // 80

#define HS_FLOATS (NHROWS*HSTR)    // 10560
#define BUF_FLOATS (40*QSTR)       // 2720 (half-batch 40-row buffer)
#define P_FLOATS (BT*TS*12)        // 960
#define LDS_FLOATS (HS_FLOATS + 3*BUF_FLOATS + P_FLOATS)   // 19680 -> 78720 B (2 WG/CU)

#define INVSQRT10 0.31622776601683794f

// ---------------- POS precompute (fp64, once per launch, into d_ws) ----------
__global__ void pos_kernel(float* __restrict__ pos) {
    for (int idx = threadIdx.x; idx < TS * TD; idx += blockDim.x) {
        int n = idx / TD, d = idx % TD;
        int j = d >> 1;
        double ang = (double)n / pow(1000.0, 2.0 * (double)j / (double)TD);
        double v = (d & 1) ? cos(ang) : sin(ang);
        pos[idx] = (float)v;
    }
}

// ---------------- M-row x C-col fp32 GEMM tile ------------------------------
// OUT[m][c] = sum_k A[row(m)+k] * W[k*ws+c], row(m) = a0 + (m/SPLIT)*aHi + (m%SPLIT)*aLo.
// A,O in LDS; W in global. K multiple of 8, register double-buffered (prefetch
// k+4 before computing k). Addressing strength-reduced: two running pointers
// advanced by constants; all load offsets are compile-time immediates.
template <int M, int SPLIT, int C, int K, bool ADD>
__device__ __forceinline__ void gemm_f32(
    const float* __restrict__ Ap, int a0, int aHi, int aLo,
    const float* __restrict__ W, int ws,
    float* __restrict__ Op, int o0, int oHi, int oLo,
    float scale)
{
    constexpr int CG = C / 4;
    float acc[M][C];
#pragma unroll
    for (int m = 0; m < M; m++)
#pragma unroll
        for (int c = 0; c < C; c++) acc[m][c] = 0.f;

    float4 aR0[M], aR1[M], wR0[4 * CG], wR1[4 * CG];
    const float* ap = Ap + a0;
    const float* wp = W;

    auto loadW = [&](float4* wR, const float* w) {
#pragma unroll
        for (int kk = 0; kk < 4; kk++)
#pragma unroll
            for (int cg = 0; cg < CG; cg++)
                wR[kk * CG + cg] = *(const float4*)(w + kk * ws + cg * 4);
    };
    auto loadA = [&](float4* aR, const float* a) {
#pragma unroll
        for (int m = 0; m < M; m++)
            aR[m] = *(const float4*)(a + (m / SPLIT) * aHi + (m % SPLIT) * aLo);
    };
    auto compute = [&](const float4* aR, const float4* wR) {
#pragma unroll
        for (int m = 0; m < M; m++) {
            const float* af = (const float*)&aR[m];
#pragma unroll
            for (int kk = 0; kk < 4; kk++) {
                float a = af[kk];
#pragma unroll
                for (int cg = 0; cg < CG; cg++) {
                    const float* wf = (const float*)&wR[kk * CG + cg];
#pragma unroll
                    for (int j = 0; j < 4; j++)
                        acc[m][cg * 4 + j] = fmaf(a, wf[j], acc[m][cg * 4 + j]);
                }
            }
        }
    };

    loadW(wR0, wp); loadA(aR0, ap);
#pragma unroll 1
    for (int k = 0; k + 8 < K; k += 8) {
        loadW(wR1, wp + 4 * ws); loadA(aR1, ap + 4);   // prefetch k+4
        compute(aR0, wR0);                              // compute k
        wp += 8 * ws; ap += 8;
        loadW(wR0, wp); loadA(aR0, ap);                 // prefetch k+8
        compute(aR1, wR1);                              // compute k+4
    }
    loadW(wR1, wp + 4 * ws); loadA(aR1, ap + 4);        // K-4
    compute(aR0, wR0);                                  // K-8
    compute(aR1, wR1);                                  // K-4

#pragma unroll
    for (int m = 0; m < M; m++) {
        float* op = Op + o0 + (m / SPLIT) * oHi + (m % SPLIT) * oLo;
#pragma unroll
        for (int cg = 0; cg < CG; cg++) {
            float4 r;
            if constexpr (ADD) {
                float4 v = *(float4*)(op + cg * 4);
                r.x = fmaf(scale, acc[m][cg * 4 + 0], v.x);
                r.y = fmaf(scale, acc[m][cg * 4 + 1], v.y);
                r.z = fmaf(scale, acc[m][cg * 4 + 2], v.z);
                r.w = fmaf(scale, acc[m][cg * 4 + 3], v.w);
            } else {
                r.x = scale * acc[m][cg * 4 + 0];
                r.y = scale * acc[m][cg * 4 + 1];
                r.z = scale * acc[m][cg * 4 + 2];
                r.w = scale * acc[m][cg * 4 + 3];
            }
            *(float4*)(op + cg * 4) = r;
        }
    }
}

// ---------------- fused kernel ----------------------------------------------
// BT=8, hb-split (4 batches per half), 78.72 KB LDS -> 2 WG/CU (LDS-capped,
// so VGPR up to 256 is free). M=8 tiles = 4 batches x (n, n+5).
extern "C" __global__ __launch_bounds__(NTHR, 2)
void trans_fused(const float* __restrict__ x,
                 const float* __restrict__ L_w, const float* __restrict__ UL_w,
                 const float* __restrict__ WQ,  const float* __restrict__ WK,
                 const float* __restrict__ WVd, const float* __restrict__ WVu,
                 const float* __restrict__ WQ2, const float* __restrict__ WK2,
                 const float* __restrict__ WVd2,const float* __restrict__ WVu2,
                 const float* __restrict__ qin1,const float* __restrict__ qout1,
                 const float* __restrict__ qin2,const float* __restrict__ qout2,
                 const float* __restrict__ POSb, float* __restrict__ out)
{
    extern __shared__ float lds[];
    float* Hs = lds;                      // [80][HSTR], row = b*10 + n
    float* Qb = lds + HS_FLOATS;          // [40][QSTR], row r2 = b4*10 + n ; also G, t(lo)
    float* Kb = Qb + BUF_FLOATS;          // [40][QSTR]                     ; also t(hi)
    float* Vb = Kb + BUF_FLOATS;          // [40][QSTR] Vd
    float* Pb = Vb + BUF_FLOATS;          // [8][10][12] logits -> softmax weights
    float* Tb = Qb;                       // t: 80 rows spanning Qb+Kb

    const int tid = threadIdx.x;
    const int vtid = (tid + ((blockIdx.x & 3) << 6)) & 255;  // rotate idle windows
    const int gb0 = blockIdx.x * BT;

    // ---- Phase 0: h = x @ L_w + POS (fp64 accum) ----
    for (int idx = tid; idx < NHROWS * TD; idx += NTHR) {
        int r = idx >> 7, d = idx & 127;
        int b = r / 10, n = r - b * 10;
        const float* xp = x + ((size_t)(gb0 + b) * TS + n) * 4;
        double acc = (double)POSb[n * TD + d];
#pragma unroll
        for (int c = 0; c < 4; c++)
            acc += (double)xp[c] * (double)L_w[c * TD + d];
        Hs[r * HSTR + d] = (float)acc;
    }
    __syncthreads();

    for (int layer = 0; layer < 2; ++layer) {
        const float* pWQ  = layer ? WQ2  : WQ;
        const float* pWK  = layer ? WK2  : WK;
        const float* pWVd = layer ? WVd2 : WVd;
        const float* pWVu = layer ? WVu2 : WVu;
        const float* pqin = layer ? qin2 : qin1;
        const float* pqou = layer ? qout2 : qout1;

        for (int hb = 0; hb < 2; ++hb) {
            // batches b = hb*4 + b4; Hs rows (hb*4+b4)*10 + n
            // ---- QKV: 240 tasks = mat(3) x np(5) x cg(16); M=8 = b4(4) x (n,n+5) ----
            if (vtid < 240) {
                int p = vtid / 80, t2 = vtid % 80;
                int np = t2 >> 4, cg = t2 & 15;
                const float* Wp = (p == 0 ? pWQ : (p == 1 ? pWK : pWVd)) + cg * 4;
                float* Ob = (p == 0 ? Qb : (p == 1 ? Kb : Vb));
                gemm_f32<8, 2, 4, TD, false>(
                    Hs, (hb * 40 + np) * HSTR, 10 * HSTR, 5 * HSTR,
                    Wp, TE,
                    Ob, np * QSTR + cg * 4, 10 * QSTR, 5 * QSTR, 1.f);
            }
            __syncthreads();

            // ---- logits (fp64, 2 chains): 220 = b4(4) x 55 (i,j<=i) ----
            if (vtid < 220) {
                int b4 = vtid / 55, pr = vtid % 55;
                int i = 0, base = 0;
                while (pr >= base + i + 1) { base += i + 1; i++; }
                int j = pr - base;
                const float* qr = Qb + (b4 * 10 + i) * QSTR;
                const float* kr = Kb + (b4 * 10 + j) * QSTR;
                double acc0 = 0.0, acc1 = 0.0;
                for (int e = 0; e < TE; e += 8) {
                    float4 qa = *(const float4*)(qr + e);
                    float4 ka = *(const float4*)(kr + e);
                    float4 qc = *(const float4*)(qr + e + 4);
                    float4 kc = *(const float4*)(kr + e + 4);
                    acc0 = fma((double)qa.x, (double)ka.x, acc0);
                    acc1 = fma((double)qc.x, (double)kc.x, acc1);
                    acc0 = fma((double)qa.y, (double)ka.y, acc0);
                    acc1 = fma((double)qc.y, (double)kc.y, acc1);
                    acc0 = fma((double)qa.z, (double)ka.z, acc0);
                    acc1 = fma((double)qc.z, (double)kc.z, acc1);
                    acc0 = fma((double)qa.w, (double)ka.w, acc0);
                    acc1 = fma((double)qc.w, (double)kc.w, acc1);
                }
                Pb[(hb * 4 + b4) * 120 + i * 12 + j] = (float)(acc0 + acc1);
            }
            __syncthreads();

            // ---- softmax over keys j<=i (fp32, matches reference) ----
            if (vtid < 40) {
                int b4 = vtid / 10, i = vtid % 10;
                float* pr = Pb + (hb * 4 + b4) * 120 + i * 12;
                float m = pr[0];
#pragma unroll
                for (int j = 1; j < TS; j++) if (j <= i) m = fmaxf(m, pr[j]);
                float sum = 0.f;
#pragma unroll
                for (int j = 0; j < TS; j++) if (j <= i) { float e = expf(pr[j] - m); pr[j] = e; sum += e; }
#pragma unroll
                for (int j = 0; j < TS; j++) pr[j] = (j <= i) ? pr[j] / sum : 0.f;
            }
            __syncthreads();

            // ---- G[r2=b4*10+q][e] = sum_k P * Vd[b4*10+k][e]; into Qb (Q dead) ----
            for (int oi = vtid; oi < 40 * 16; oi += NTHR) {
                int rr = oi >> 4, e4 = (oi & 15) * 4;
                int b4 = rr / 10, q = rr - b4 * 10;
                const float* pp = Pb + (hb * 4 + b4) * 120 + q * 12;
                float4 g = {0.f, 0.f, 0.f, 0.f};
#pragma unroll
                for (int k = 0; k < TS; k++) {
                    float p = pp[k];
                    float4 v = *(const float4*)(Vb + (b4 * 10 + k) * QSTR + e4);
                    g.x = fmaf(p, v.x, g.x);
                    g.y = fmaf(p, v.y, g.y);
                    g.z = fmaf(p, v.z, g.z);
                    g.w = fmaf(p, v.w, g.w);
                }
                *(float4*)(Qb + rr * QSTR + e4) = g;
            }
            __syncthreads();

            // ---- DE: Hs(half) += invsqrt10 * G @ WVu ; 160 = qp(5) x cg(32), M=8 ----
            if (vtid < 160) {
                int qp = vtid >> 5, cg = vtid & 31;
                gemm_f32<8, 2, 4, TE, true>(
                    Qb, qp * QSTR, 10 * QSTR, 5 * QSTR,
                    pWVu + cg * 4, TD,
                    Hs, (hb * 40 + qp) * HSTR + cg * 4, 10 * HSTR, 5 * HSTR,
                    INVSQRT10);
            }
            __syncthreads();
        } // hb

        // ---- ques-in: t[80][64] = Hs @ quesin[n]; 160 = n(10) x cg(16), M=8 over b ----
        if (vtid < 160) {
            int n = vtid >> 4, cg = vtid & 15;
            gemm_f32<8, 1, 4, TD, false>(
                Hs, n * HSTR, 10 * HSTR, 0,
                pqin + (size_t)n * TD * TE + cg * 4, TE,
                Tb, n * QSTR + cg * 4, 10 * QSTR, 0, 1.f);
        }
        __syncthreads();

        // ---- ques-out: Hs = t @ quesout[n]; 160 = n(10) x cg(16), M=8 C=8 ----
        if (vtid < 160) {
            int n = vtid >> 4, cg = vtid & 15;
            gemm_f32<8, 1, 8, TE, false>(
                Tb, n * QSTR, 10 * QSTR, 0,
                pqou + (size_t)n * TE * TD + cg * 8, TD,
                Hs, n * HSTR + cg * 8, 10 * HSTR, 0, 1.f);
        }
        __syncthreads();
    } // layer

    // ---- out = Hs @ UL_w : 320 outs, rotated grid-stride ----
    for (int idx = vtid; idx < NHROWS * 4; idx += NTHR) {
        int r = idx >> 2, c = idx & 3;
        int b = r / 10, n = r - b * 10;
        const float* hr = Hs + r * HSTR;
        float acc = 0.f;
        for (int d = 0; d < TD; d += 4) {
            float4 h4 = *(const float4*)(hr + d);
            acc = fmaf(h4.x, UL_w[(d + 0) * 4 + c], acc);
            acc = fmaf(h4.y, UL_w[(d + 1) * 4 + c], acc);
            acc = fmaf(h4.z, UL_w[(d + 2) * 4 + c], acc);
            acc = fmaf(h4.w, UL_w[(d + 3) * 4 + c], acc);
        }
        out[((size_t)(gb0 + b) * TS + n) * 4 + c] = acc;
    }
}

// ---------------- host launch -----------------------------------------------
extern "C" void kernel_launch(void* const* d_in, const int* in_sizes, int n_in,
                              void* d_out, int out_size, void* d_ws, size_t ws_size,
                              hipStream_t stream) {
    const float* x    = (const float*)d_in[0];
    const float* L_w  = (const float*)d_in[1];
    const float* UL_w = (const float*)d_in[2];
    const float* WQ   = (const float*)d_in[3];
    const float* WK   = (const float*)d_in[4];
    const float* WVd  = (const float*)d_in[5];
    const float* WVu  = (const float*)d_in[6];
    const float* WQ2  = (const float*)d_in[7];
    const float* WK2  = (const float*)d_in[8];
    const float* WVd2 = (const float*)d_in[9];
    const float* WVu2 = (const float*)d_in[10];
    const float* qin1 = (const float*)d_in[11];
    const float* qout1= (const float*)d_in[12];
    const float* qin2 = (const float*)d_in[13];
    const float* qout2= (const float*)d_in[14];
    float* out = (float*)d_out;
    float* POSb = (float*)d_ws;

    int B = in_sizes[0] / (TS * 4);
    size_t lds_bytes = (size_t)LDS_FLOATS * sizeof(float);

    (void)hipFuncSetAttribute((const void*)trans_fused,
                              hipFuncAttributeMaxDynamicSharedMemorySize,
                              (int)lds_bytes);

    pos_kernel<<<dim3(1), dim3(256), 0, stream>>>(POSb);
    trans_fused<<<dim3(B / BT), dim3(NTHR), lds_bytes, stream>>>(
        x, L_w, UL_w, WQ, WK, WVd, WVu, WQ2, WK2, WVd2, WVu2,
        qin1, qout1, qin2, qout2, POSb, out);
}